// Round 9
// baseline (539.407 us; speedup 1.0000x reference)
//
#include <hip/hip_runtime.h>
#include <hip/hip_fp16.h>

#define N_NODES 200000
#define N_EDGES 6400000
#define N_GRAPHS 512

#define NB 3125      // 64-node dst buckets: 3125*64 = 200000 exactly
#define CHUNK 4096
#define NCH 1563     // 1563*4096 = 6,402,048 >= 6.4M (last chunk partial)
#define NGRP 25      // chunk groups for parallel scan
#define CPG 63       // chunks per group: 25*63 = 1575 >= 1563
#define SEG 13       // 256*13 = 3328 >= NB
#define SCAP 3072    // max edges per 64-node bucket (mean 2048)
#define ECAP64 2816  // LDS edge cap, 64-node block (mean 2048, sd 45: +17 sigma)
#define ECAP32 1536  // LDS edge cap, 32-node block (mean 1024, sd 32: +16 sigma)

// ---------- non-temporal helpers ----------
typedef float vf4 __attribute__((ext_vector_type(4)));
typedef float vf2 __attribute__((ext_vector_type(2)));
typedef unsigned vu2 __attribute__((ext_vector_type(2)));

__device__ __forceinline__ unsigned ntload_u(const unsigned* p) {
  return __builtin_nontemporal_load(p);
}
__device__ __forceinline__ int ntload_i(const int* p) { return __builtin_nontemporal_load(p); }
__device__ __forceinline__ float ntload_f(const float* p) {
  return __builtin_nontemporal_load(p);
}
__device__ __forceinline__ float2 ntload_f2(const float* p) {
  vf2 v = __builtin_nontemporal_load((const vf2*)p);
  return make_float2(v.x, v.y);
}
__device__ __forceinline__ void ntstore_u2(unsigned* p, uint2 v) {
  vu2 t = {v.x, v.y};
  __builtin_nontemporal_store(t, (vu2*)p);
}
__device__ __forceinline__ void ntstore_f2(float* p, float2 v) {
  vf2 t = {v.x, v.y};
  __builtin_nontemporal_store(t, (vf2*)p);
}
__device__ __forceinline__ void ntstore_f4(float* p, float4 v) {
  vf4 t = {v.x, v.y, v.z, v.w};
  __builtin_nontemporal_store(t, (vf4*)p);
}
__device__ __forceinline__ void ntstore_u(unsigned* p, unsigned v) {
  __builtin_nontemporal_store(v, p);
}

// ---------- partition pass 1: counting sort of edges by dst>>6 ----------
// H (ushort) TRANSPOSED: H[c*NB + b]

__global__ __launch_bounds__(256) void count_kernel(const int* __restrict__ dst,
                                                    unsigned short* __restrict__ H) {
  __shared__ unsigned hist[NB];
  for (int i = threadIdx.x; i < NB; i += 256) hist[i] = 0;
  __syncthreads();
  int c = blockIdx.x;
  long e0 = (long)c * CHUNK;
  long rem = (long)N_EDGES - e0;
  int n = rem > CHUNK ? CHUNK : (int)rem;
  for (int i = threadIdx.x; i < n; i += 256) atomicAdd(&hist[dst[e0 + i] >> 6], 1u);
  __syncthreads();
  for (int i = threadIdx.x; i < NB; i += 256) H[(size_t)c * NB + i] = (unsigned short)hist[i];
}

__global__ __launch_bounds__(256) void scan_bins1_kernel(unsigned short* __restrict__ H,
                                                         unsigned* __restrict__ P) {
  int b = blockIdx.x * 256 + threadIdx.x;
  int g = blockIdx.y;
  if (b >= NB) return;
  int c0 = g * CPG, c1 = min(NCH, (g + 1) * CPG);
  unsigned run = 0;
  for (int c = c0; c < c1; c++) {
    unsigned t = H[(size_t)c * NB + b];
    H[(size_t)c * NB + b] = (unsigned short)run;
    run += t;
  }
  P[(size_t)g * NB + b] = run;
}

__global__ __launch_bounds__(256) void scan_bins2_kernel(unsigned* __restrict__ P,
                                                         unsigned* __restrict__ bucketTotal) {
  int b = blockIdx.x * 256 + threadIdx.x;
  if (b >= NB) return;
  unsigned run = 0;
  for (int g = 0; g < NGRP; g++) {
    unsigned t = P[(size_t)g * NB + b];
    P[(size_t)g * NB + b] = run;
    run += t;
  }
  bucketTotal[b] = run;
}

// exclusive scan of totals -> bucketStart[NB+1] (one block)
__global__ __launch_bounds__(256) void scan_total_kernel(const unsigned* __restrict__ bucketTotal,
                                                         unsigned* __restrict__ bucketStart) {
  __shared__ unsigned sv[256 * SEG];
  __shared__ unsigned partial[256];
  int t = threadIdx.x;
  for (int i = t; i < 256 * SEG; i += 256) sv[i] = (i < NB) ? bucketTotal[i] : 0u;
  __syncthreads();
  unsigned sum = 0;
#pragma unroll
  for (int k = 0; k < SEG; k++) sum += sv[t * SEG + k];
  partial[t] = sum;
  __syncthreads();
  for (int off = 1; off < 256; off <<= 1) {
    unsigned add = (t >= off) ? partial[t - off] : 0u;
    __syncthreads();
    partial[t] += add;
    __syncthreads();
  }
  unsigned run = partial[t] - sum;
#pragma unroll
  for (int k = 0; k < SEG; k++) {
    unsigned w = sv[t * SEG + k];
    sv[t * SEG + k] = run;
    run += w;
  }
  __syncthreads();
  for (int i = t; i < NB; i += 256) bucketStart[i] = sv[i];
  if (t == 0) bucketStart[NB] = N_EDGES;
}

// chunk-local LDS counting sort by bucket, coalesced-run writes -> packedA = (src<<7)|dl
__global__ __launch_bounds__(256) void scatter_sorted_kernel(
    const int* __restrict__ src, const int* __restrict__ dst,
    const unsigned short* __restrict__ H, const unsigned* __restrict__ P,
    const unsigned* __restrict__ bucketStart, unsigned* __restrict__ packed) {
  __shared__ unsigned ssort[CHUNK];        // 16 KB
  __shared__ unsigned short sbort[CHUNK];  // 8 KB
  __shared__ unsigned hist[3328];          // 13.3 KB
  __shared__ unsigned cur[3328];           // 13.3 KB
  __shared__ unsigned partial[256];
  int t = threadIdx.x;
  int c = blockIdx.x;
  int g = c / CPG;
  long e0 = (long)c * CHUNK;
  long rem = (long)N_EDGES - e0;
  int n = rem > CHUNK ? CHUNK : (int)rem;
  for (int i = t; i < 3328; i += 256) hist[i] = 0;
  __syncthreads();
  for (int i = t; i < n; i += 256) atomicAdd(&hist[dst[e0 + i] >> 6], 1u);
  __syncthreads();
  unsigned a[SEG], sum = 0;
#pragma unroll
  for (int k = 0; k < SEG; k++) { a[k] = hist[SEG * t + k]; sum += a[k]; }
  partial[t] = sum;
  __syncthreads();
  for (int off = 1; off < 256; off <<= 1) {
    unsigned add = (t >= off) ? partial[t - off] : 0u;
    __syncthreads();
    partial[t] += add;
    __syncthreads();
  }
  unsigned run = partial[t] - sum;
#pragma unroll
  for (int k = 0; k < SEG; k++) {
    hist[SEG * t + k] = run;
    cur[SEG * t + k] = run;
    run += a[k];
  }
  __syncthreads();
  for (int i = t; i < n; i += 256) {
    int d = dst[e0 + i], s = src[e0 + i];
    int b = d >> 6;
    unsigned r = atomicAdd(&cur[b], 1u);
    ssort[r] = ((unsigned)s << 7) | (unsigned)(d & 63);
    sbort[r] = (unsigned short)b;
  }
  __syncthreads();
  for (int b = t; b < NB; b += 256)
    cur[b] = bucketStart[b] + P[(size_t)g * NB + b] + H[(size_t)c * NB + b] - hist[b];
  __syncthreads();
  for (int j = t; j < n; j += 256) packed[cur[sbort[j]] + j] = ssort[j];
}

// ---------- partition pass 2: within-bucket sort by node -> full CSR ----------
__global__ __launch_bounds__(256) void sort2_kernel(const unsigned* __restrict__ packedA,
                                                    const unsigned* __restrict__ bucketStart,
                                                    unsigned* __restrict__ packedB,
                                                    unsigned* __restrict__ nodeStart) {
  __shared__ unsigned buf[SCAP];
  __shared__ unsigned buf2[SCAP];
  __shared__ unsigned hist[64], base[64], cur[64];
  int t = threadIdx.x, b = blockIdx.x;
  unsigned s0 = bucketStart[b], s1 = bucketStart[b + 1];
  int n = (int)(s1 - s0);
  if (t < 64) hist[t] = 0;
  for (int i = t; i < n; i += 256) buf[i] = packedA[s0 + i];
  __syncthreads();
  for (int i = t; i < n; i += 256) atomicAdd(&hist[buf[i] & 63u], 1u);
  __syncthreads();
  if (t == 0) {
    unsigned run = 0;
    for (int k = 0; k < 64; k++) {
      unsigned v = hist[k];
      base[k] = run;
      cur[k] = run;
      run += v;
    }
  }
  __syncthreads();
  if (t < 64) nodeStart[b * 64 + t] = s0 + base[t];
  for (int i = t; i < n; i += 256) {
    unsigned p = buf[i];
    unsigned pos = atomicAdd(&cur[p & 63u], 1u);
    buf2[pos] = p >> 7;  // store src only; node implied by CSR position
  }
  __syncthreads();
  for (int i = t; i < n; i += 256) packedB[s0 + i] = buf2[i];
  if (b == NB - 1 && t == 0) nodeStart[N_NODES] = N_EDGES;
}

// ---------- xpad ----------
__global__ __launch_bounds__(256) void xpad_kernel(const float* __restrict__ x,
                                                   float4* __restrict__ xp) {
  int n = blockIdx.x * 256 + threadIdx.x;
  if (n >= N_NODES) return;
  xp[n] = make_float4(x[3 * n], x[3 * n + 1], x[3 * n + 2], 0.f);
}

__device__ __forceinline__ void half8_unpack(uint4 g, float* f) {
  const __half2* h2 = reinterpret_cast<const __half2*>(&g);
#pragma unroll
  for (int j = 0; j < 4; j++) {
    float2 fj = __half22float2(h2[j]);
    f[2 * j] = fj.x;
    f[2 * j + 1] = fj.y;
  }
}

// ---------- layer 1: LDS-staged edges, 64 nodes/block, 4 thr/node ----------
__global__ __launch_bounds__(256) void layer1_kernel(
    const unsigned* __restrict__ packed, const unsigned* __restrict__ nodeStart,
    const float4* __restrict__ xp,
    const float* __restrict__ W1_rel, const float* __restrict__ b1,
    const float* __restrict__ W1_root,
    const float* __restrict__ W2_rel, const float* __restrict__ W2_root,
    unsigned* __restrict__ t2h, float* __restrict__ r2) {
  __shared__ float sW1rel[96], sW1root[96], sb1[32], sW2rel[512], sW2root[512];
  __shared__ unsigned sedge[ECAP64];
  __shared__ unsigned snode[65];
  __shared__ float plds[256 * 4];
  int t = threadIdx.x, blk = blockIdx.x;
  for (int i = t; i < 96; i += 256) { sW1rel[i] = W1_rel[i]; sW1root[i] = W1_root[i]; }
  for (int i = t; i < 32; i += 256) sb1[i] = b1[i];
  for (int i = t; i < 512; i += 256) { sW2rel[i] = W2_rel[i]; sW2root[i] = W2_root[i]; }
  if (t < 65) snode[t] = ntload_u(&nodeStart[blk * 64 + t]);
  __syncthreads();
  unsigned ebase = snode[0];
  int nE = (int)(snode[64] - ebase);
  for (int i = t; i < nE; i += 256) sedge[i] = ntload_u(&packed[ebase + i]);
  __syncthreads();
  int ln = t >> 2, part = t & 3;
  int node = blk * 64 + ln;
  unsigned s1v = snode[ln + 1] - ebase;
  float a0 = 0.f, a1 = 0.f, a2 = 0.f;
  for (unsigned u = snode[ln] - ebase + part; u < s1v; u += 16) {
    unsigned i1 = u + 4, i2 = u + 8, i3 = u + 12;
    unsigned e0 = sedge[u];
    unsigned e1 = sedge[(i1 < s1v) ? i1 : u];
    unsigned e2 = sedge[(i2 < s1v) ? i2 : u];
    unsigned e3 = sedge[(i3 < s1v) ? i3 : u];
    float4 g0 = xp[e0], g1 = xp[e1], g2 = xp[e2], g3 = xp[e3];
    float m1 = (i1 < s1v) ? 1.f : 0.f;
    float m2 = (i2 < s1v) ? 1.f : 0.f;
    float m3 = (i3 < s1v) ? 1.f : 0.f;
    a0 += g0.x + m1 * g1.x + m2 * g2.x + m3 * g3.x;
    a1 += g0.y + m1 * g1.y + m2 * g2.y + m3 * g3.y;
    a2 += g0.z + m1 * g1.z + m2 * g2.z + m3 * g3.z;
  }
  plds[t * 4] = a0; plds[t * 4 + 1] = a1; plds[t * 4 + 2] = a2;
  __syncthreads();
  int pb = ln * 16;
  float A0 = plds[pb] + plds[pb + 4] + plds[pb + 8] + plds[pb + 12];
  float A1 = plds[pb + 1] + plds[pb + 5] + plds[pb + 9] + plds[pb + 13];
  float A2 = plds[pb + 2] + plds[pb + 6] + plds[pb + 10] + plds[pb + 14];
  float4 xv = xp[node];
  float h[32];
#pragma unroll
  for (int k = 0; k < 32; k++) {
    float v = sW1rel[3 * k] * A0 + sW1rel[3 * k + 1] * A1 + sW1rel[3 * k + 2] * A2 +
              sW1root[3 * k] * xv.x + sW1root[3 * k + 1] * xv.y + sW1root[3 * k + 2] * xv.z +
              sb1[k];
    h[k] = fmaxf(v, 0.f);
  }
  int jb = part * 4;
  float tv[4], rv[4];
#pragma unroll
  for (int j = 0; j < 4; j++) {
    float acc = 0.f, accr = 0.f;
#pragma unroll
    for (int k = 0; k < 32; k++) {
      acc += sW2rel[32 * (jb + j) + k] * h[k];
      accr += sW2root[32 * (jb + j) + k] * h[k];
    }
    tv[j] = acc;
    rv[j] = accr;
  }
  __half2 p0 = __halves2half2(__float2half_rn(tv[0]), __float2half_rn(tv[1]));
  __half2 p1 = __halves2half2(__float2half_rn(tv[2]), __float2half_rn(tv[3]));
  ntstore_u2(&t2h[(size_t)node * 8 + part * 2], make_uint2(*(unsigned*)&p0, *(unsigned*)&p1));
  ntstore_f4(&r2[(size_t)node * 16 + jb], make_float4(rv[0], rv[1], rv[2], rv[3]));
}

// ---------- layer 2: LDS-staged edges, 32 nodes/block, 8 thr/node, full 32B/edge ----------
__global__ __launch_bounds__(256) void layer2_kernel(
    const unsigned* __restrict__ packed, const unsigned* __restrict__ nodeStart,
    const uint4* __restrict__ t2h4, const float* __restrict__ r2,
    const float* __restrict__ b2,
    const float* __restrict__ W3_rel, const float* __restrict__ W3_root,
    unsigned* __restrict__ t3h, float* __restrict__ r3) {
  __shared__ float sW3rel[128], sW3root[128], sb2[16];
  __shared__ unsigned sedge[ECAP32];
  __shared__ unsigned snode[33];
  __shared__ float plds[256 * 17];  // stride 17: conflict-free combine
  __shared__ float hlds[32 * 16];
  int t = threadIdx.x, blk = blockIdx.x;
  for (int i = t; i < 128; i += 256) { sW3rel[i] = W3_rel[i]; sW3root[i] = W3_root[i]; }
  if (t < 16) sb2[t] = b2[t];
  if (t < 33) snode[t] = ntload_u(&nodeStart[blk * 32 + t]);
  __syncthreads();
  unsigned ebase = snode[0];
  int nE = (int)(snode[32] - ebase);
  for (int i = t; i < nE; i += 256) sedge[i] = ntload_u(&packed[ebase + i]);
  __syncthreads();
  int ln = t >> 3, p = t & 7;
  int node = blk * 32 + ln;
  unsigned s1v = snode[ln + 1] - ebase;
  float acc[16];
#pragma unroll
  for (int j = 0; j < 16; j++) acc[j] = 0.f;
  for (unsigned u = snode[ln] - ebase + p; u < s1v; u += 32) {
    unsigned i1 = u + 8, i2 = u + 16, i3 = u + 24;
    unsigned e0 = sedge[u];
    unsigned e1 = sedge[(i1 < s1v) ? i1 : u];
    unsigned e2 = sedge[(i2 < s1v) ? i2 : u];
    unsigned e3 = sedge[(i3 < s1v) ? i3 : u];
    uint4 ga0 = t2h4[(size_t)e0 * 2], gb0 = t2h4[(size_t)e0 * 2 + 1];
    uint4 ga1 = t2h4[(size_t)e1 * 2], gb1 = t2h4[(size_t)e1 * 2 + 1];
    uint4 ga2 = t2h4[(size_t)e2 * 2], gb2 = t2h4[(size_t)e2 * 2 + 1];
    uint4 ga3 = t2h4[(size_t)e3 * 2], gb3 = t2h4[(size_t)e3 * 2 + 1];
    float m1 = (i1 < s1v) ? 1.f : 0.f;
    float m2 = (i2 < s1v) ? 1.f : 0.f;
    float m3 = (i3 < s1v) ? 1.f : 0.f;
    float f0[8], f1[8], f2[8], f3[8];
    half8_unpack(ga0, f0); half8_unpack(ga1, f1);
    half8_unpack(ga2, f2); half8_unpack(ga3, f3);
#pragma unroll
    for (int j = 0; j < 8; j++) acc[j] += f0[j] + m1 * f1[j] + m2 * f2[j] + m3 * f3[j];
    half8_unpack(gb0, f0); half8_unpack(gb1, f1);
    half8_unpack(gb2, f2); half8_unpack(gb3, f3);
#pragma unroll
    for (int j = 0; j < 8; j++) acc[8 + j] += f0[j] + m1 * f1[j] + m2 * f2[j] + m3 * f3[j];
  }
#pragma unroll
  for (int j = 0; j < 16; j++) plds[t * 17 + j] = acc[j];
  __syncthreads();
  // h: thread computes feats 2p, 2p+1 (sum over 8 partials)
  {
    float2 rv = ntload_f2(&r2[(size_t)node * 16 + 2 * p]);
    float hv[2];
#pragma unroll
    for (int k2 = 0; k2 < 2; k2++) {
      int f = 2 * p + k2;
      int q0 = (ln * 8) * 17 + f;
      float s = 0.f;
#pragma unroll
      for (int q = 0; q < 8; q++) s += plds[q0 + q * 17];
      hv[k2] = s + sb2[f] + (k2 == 0 ? rv.x : rv.y);
    }
    hlds[ln * 16 + 2 * p] = fmaxf(hv[0], 0.f);
    hlds[ln * 16 + 2 * p + 1] = fmaxf(hv[1], 0.f);
  }
  __syncthreads();
  // rows: p<4 -> W3_rel rows 2p,2p+1 (t3); p>=4 -> W3_root rows 2(p-4).. (r3)
  const float* W = (p < 4) ? sW3rel : sW3root;
  int rbase = (p < 4) ? 2 * p : 2 * (p - 4);
  float o0 = 0.f, o1 = 0.f;
#pragma unroll
  for (int k = 0; k < 16; k++) {
    float hv = hlds[ln * 16 + k];
    o0 += W[16 * rbase + k] * hv;
    o1 += W[16 * (rbase + 1) + k] * hv;
  }
  if (p < 4) {
    __half2 pk = __halves2half2(__float2half_rn(o0), __float2half_rn(o1));
    ntstore_u(&t3h[(size_t)node * 4 + p], *(unsigned*)&pk);
  } else {
    ntstore_f2(&r3[(size_t)node * 8 + rbase], make_float2(o0, o1));
  }
}

// ---------- layer 3: LDS-staged edges, 64 nodes/block, 4 thr/node ----------
__global__ __launch_bounds__(256) void layer3_kernel(
    const unsigned* __restrict__ packed, const unsigned* __restrict__ nodeStart,
    const uint4* __restrict__ t3h4, const float* __restrict__ r3,
    const float* __restrict__ b3,
    const int* __restrict__ batch, unsigned* __restrict__ pooled) {
  __shared__ unsigned sedge[ECAP64];
  __shared__ unsigned snode[65];
  __shared__ float plds[256 * 9];
  __shared__ float sb3[8];
  int t = threadIdx.x, blk = blockIdx.x;
  if (t < 8) sb3[t] = b3[t];
  if (t < 65) snode[t] = ntload_u(&nodeStart[blk * 64 + t]);
  __syncthreads();
  unsigned ebase = snode[0];
  int nE = (int)(snode[64] - ebase);
  for (int i = t; i < nE; i += 256) sedge[i] = ntload_u(&packed[ebase + i]);
  __syncthreads();
  int ln = t >> 2, p = t & 3;
  unsigned s1v = snode[ln + 1] - ebase;
  float acc[8];
#pragma unroll
  for (int j = 0; j < 8; j++) acc[j] = 0.f;
  for (unsigned u = snode[ln] - ebase + p; u < s1v; u += 16) {
    unsigned i1 = u + 4, i2 = u + 8, i3 = u + 12;
    unsigned e0 = sedge[u];
    unsigned e1 = sedge[(i1 < s1v) ? i1 : u];
    unsigned e2 = sedge[(i2 < s1v) ? i2 : u];
    unsigned e3 = sedge[(i3 < s1v) ? i3 : u];
    uint4 g0 = t3h4[e0], g1 = t3h4[e1], g2 = t3h4[e2], g3 = t3h4[e3];
    float m1 = (i1 < s1v) ? 1.f : 0.f;
    float m2 = (i2 < s1v) ? 1.f : 0.f;
    float m3 = (i3 < s1v) ? 1.f : 0.f;
    float f0[8], f1[8], f2[8], f3[8];
    half8_unpack(g0, f0); half8_unpack(g1, f1);
    half8_unpack(g2, f2); half8_unpack(g3, f3);
#pragma unroll
    for (int j = 0; j < 8; j++) acc[j] += f0[j] + m1 * f1[j] + m2 * f2[j] + m3 * f3[j];
  }
#pragma unroll
  for (int j = 0; j < 8; j++) plds[t * 9 + j] = acc[j];
  __syncthreads();
  // combine: thread -> node t>>2, feats (t&3)*2 .. +1
  int cn = t >> 2;
  int node2 = blk * 64 + cn;
  int f0i = (t & 3) * 2;
  int gg = ntload_i(&batch[node2]);
  float2 rv = ntload_f2(&r3[(size_t)node2 * 8 + f0i]);
  int q0 = cn * 36 + f0i;  // (cn*4+q)*9 + f
#pragma unroll
  for (int k2 = 0; k2 < 2; k2++) {
    float v = plds[q0 + k2] + plds[q0 + 9 + k2] + plds[q0 + 18 + k2] + plds[q0 + 27 + k2];
    float h = fmaxf(v + sb3[f0i + k2] + (k2 == 0 ? rv.x : rv.y), 0.f);
    atomicMax(&pooled[8 * gg + f0i + k2], __float_as_uint(h));  // relu>=0: uint==float order
  }
}

__global__ __launch_bounds__(256) void final_kernel(
    const unsigned* __restrict__ pooled, const float* __restrict__ W_lin,
    const float* __restrict__ b_lin, float* __restrict__ out) {
  int g = blockIdx.x * blockDim.x + threadIdx.x;
  if (g >= N_GRAPHS) return;
  float acc = b_lin[0];
#pragma unroll
  for (int f = 0; f < 8; f++) acc += __uint_as_float(pooled[8 * g + f]) * W_lin[f];
  out[g] = acc;
}

extern "C" void kernel_launch(void* const* d_in, const int* in_sizes, int n_in,
                              void* d_out, int out_size, void* d_ws, size_t ws_size,
                              hipStream_t stream) {
  const float* x = (const float*)d_in[0];
  const int* ei = (const int*)d_in[1];
  const int* src = ei;
  const int* dst = ei + N_EDGES;
  const int* batch = (const int*)d_in[2];
  const float* W1_rel = (const float*)d_in[3];
  const float* b1 = (const float*)d_in[4];
  const float* W1_root = (const float*)d_in[5];
  const float* W2_rel = (const float*)d_in[6];
  const float* b2 = (const float*)d_in[7];
  const float* W2_root = (const float*)d_in[8];
  const float* W3_rel = (const float*)d_in[9];
  const float* b3 = (const float*)d_in[10];
  const float* W3_root = (const float*)d_in[11];
  const float* W_lin = (const float*)d_in[12];
  const float* b_lin = (const float*)d_in[13];
  float* out = (float*)d_out;

  // ---- workspace layout (bytes), same as R8 ----
  char* ws = (char*)d_ws;
  unsigned* packedA = (unsigned*)(ws + 0);                // 25,600,000
  float* r2 = (float*)(ws + 0);                           // 12,800,000 (alias, post-sort2)
  float* r3 = (float*)(ws + 12800000);                    // 6,400,000
  unsigned* t3h = (unsigned*)(ws + 19200000);             // 3,200,000
  float4* xpad = (float4*)(ws + 22400000);                // 3,200,000
  unsigned short* H = (unsigned short*)(ws + 25600000);   // 9,768,750 (dead before packedB)
  unsigned* packedB = (unsigned*)(ws + 25600000);         // 25,600,000 + 128 pad
  unsigned* t2h = (unsigned*)(ws + 51200128);             // 6,400,000
  unsigned* pooled = (unsigned*)(ws + 57600128);          // 16,384
  unsigned* bucketStart = (unsigned*)(ws + 57616512);     // 12,504 (NB+1)
  unsigned* bucketTotal = (unsigned*)(ws + 57629016);     // 12,500
  unsigned* P = (unsigned*)(ws + 57641516);               // 312,500
  unsigned* nodeStart = (unsigned*)(ws + 57954016);       // 800,004 -> end 58,754,020

  hipMemsetAsync(pooled, 0, N_GRAPHS * 8 * sizeof(unsigned), stream);

  // partition: two-level counting sort to full dst-CSR
  count_kernel<<<NCH, 256, 0, stream>>>(dst, H);
  scan_bins1_kernel<<<dim3((NB + 255) / 256, NGRP), 256, 0, stream>>>(H, P);
  scan_bins2_kernel<<<(NB + 255) / 256, 256, 0, stream>>>(P, bucketTotal);
  scan_total_kernel<<<1, 256, 0, stream>>>(bucketTotal, bucketStart);
  scatter_sorted_kernel<<<NCH, 256, 0, stream>>>(src, dst, H, P, bucketStart, packedA);
  sort2_kernel<<<NB, 256, 0, stream>>>(packedA, bucketStart, packedB, nodeStart);
  xpad_kernel<<<(N_NODES + 255) / 256, 256, 0, stream>>>(x, xpad);  // after sort2 (aliases packedA)

  // layers: LDS-staged edge lists, atomic-free register accumulation
  layer1_kernel<<<NB, 256, 0, stream>>>(packedB, nodeStart, xpad,
                                        W1_rel, b1, W1_root, W2_rel, W2_root, t2h, r2);
  layer2_kernel<<<N_NODES / 32, 256, 0, stream>>>(packedB, nodeStart, (const uint4*)t2h, r2, b2,
                                                  W3_rel, W3_root, t3h, r3);
  layer3_kernel<<<NB, 256, 0, stream>>>(packedB, nodeStart, (const uint4*)t3h, r3, b3,
                                        batch, pooled);
  final_kernel<<<(N_GRAPHS + 255) / 256, 256, 0, stream>>>(pooled, W_lin, b_lin, out);
}

// Round 10
// 498.791 us; speedup vs baseline: 1.0814x; 1.0814x over previous
//
#include <hip/hip_runtime.h>
#include <hip/hip_fp16.h>

#define N_NODES 200000
#define N_EDGES 6400000
#define N_GRAPHS 512

#define NB 3125      // 64-node dst buckets: 3125*64 = 200000 exactly
#define CHUNK 8192
#define NCH 782      // 782*8192 = 6,406,144 >= 6.4M (last chunk partial)
#define NGRP 25      // chunk groups for parallel scan
#define CPG 32       // chunks per group: 25*32 = 800 >= 782
#define SEG 13       // 256*13 = 3328 >= NB
#define SCAP 3072    // max edges per 64-node bucket (mean 2048)

// ---------- non-temporal helpers ----------
typedef float vf4 __attribute__((ext_vector_type(4)));
typedef float vf2 __attribute__((ext_vector_type(2)));
typedef unsigned vu2 __attribute__((ext_vector_type(2)));

__device__ __forceinline__ unsigned ntload_u(const unsigned* p) {
  return __builtin_nontemporal_load(p);
}
__device__ __forceinline__ int ntload_i(const int* p) { return __builtin_nontemporal_load(p); }
__device__ __forceinline__ float ntload_f(const float* p) {
  return __builtin_nontemporal_load(p);
}
__device__ __forceinline__ float2 ntload_f2(const float* p) {
  vf2 v = __builtin_nontemporal_load((const vf2*)p);
  return make_float2(v.x, v.y);
}
__device__ __forceinline__ void ntstore_u2(unsigned* p, uint2 v) {
  vu2 t = {v.x, v.y};
  __builtin_nontemporal_store(t, (vu2*)p);
}
__device__ __forceinline__ void ntstore_f2(float* p, float2 v) {
  vf2 t = {v.x, v.y};
  __builtin_nontemporal_store(t, (vf2*)p);
}
__device__ __forceinline__ void ntstore_f4(float* p, float4 v) {
  vf4 t = {v.x, v.y, v.z, v.w};
  __builtin_nontemporal_store(t, (vf4*)p);
}
__device__ __forceinline__ void ntstore_u(unsigned* p, unsigned v) {
  __builtin_nontemporal_store(v, p);
}

// ---------- partition pass 1: counting sort of edges by dst>>6 ----------
// H (ushort) TRANSPOSED: H[c*NB + b]

__global__ __launch_bounds__(256) void count_kernel(const int* __restrict__ dst,
                                                    unsigned short* __restrict__ H) {
  __shared__ unsigned hist[NB];
  for (int i = threadIdx.x; i < NB; i += 256) hist[i] = 0;
  __syncthreads();
  int c = blockIdx.x;
  long e0 = (long)c * CHUNK;
  long rem = (long)N_EDGES - e0;
  int n = rem > CHUNK ? CHUNK : (int)rem;
  for (int i = threadIdx.x; i < n; i += 256) atomicAdd(&hist[dst[e0 + i] >> 6], 1u);
  __syncthreads();
  for (int i = threadIdx.x; i < NB; i += 256) H[(size_t)c * NB + i] = (unsigned short)hist[i];
}

__global__ __launch_bounds__(256) void scan_bins1_kernel(unsigned short* __restrict__ H,
                                                         unsigned* __restrict__ P) {
  int b = blockIdx.x * 256 + threadIdx.x;
  int g = blockIdx.y;
  if (b >= NB) return;
  int c0 = g * CPG, c1 = min(NCH, (g + 1) * CPG);
  unsigned run = 0;
  for (int c = c0; c < c1; c++) {
    unsigned t = H[(size_t)c * NB + b];
    H[(size_t)c * NB + b] = (unsigned short)run;
    run += t;
  }
  P[(size_t)g * NB + b] = run;
}

__global__ __launch_bounds__(256) void scan_bins2_kernel(unsigned* __restrict__ P,
                                                         unsigned* __restrict__ bucketTotal) {
  int b = blockIdx.x * 256 + threadIdx.x;
  if (b >= NB) return;
  unsigned run = 0;
  for (int g = 0; g < NGRP; g++) {
    unsigned t = P[(size_t)g * NB + b];
    P[(size_t)g * NB + b] = run;
    run += t;
  }
  bucketTotal[b] = run;
}

// exclusive scan of totals -> bucketStart[NB+1] (one block)
__global__ __launch_bounds__(256) void scan_total_kernel(const unsigned* __restrict__ bucketTotal,
                                                         unsigned* __restrict__ bucketStart) {
  __shared__ unsigned sv[256 * SEG];
  __shared__ unsigned partial[256];
  int t = threadIdx.x;
  for (int i = t; i < 256 * SEG; i += 256) sv[i] = (i < NB) ? bucketTotal[i] : 0u;
  __syncthreads();
  unsigned sum = 0;
#pragma unroll
  for (int k = 0; k < SEG; k++) sum += sv[t * SEG + k];
  partial[t] = sum;
  __syncthreads();
  for (int off = 1; off < 256; off <<= 1) {
    unsigned add = (t >= off) ? partial[t - off] : 0u;
    __syncthreads();
    partial[t] += add;
    __syncthreads();
  }
  unsigned run = partial[t] - sum;
#pragma unroll
  for (int k = 0; k < SEG; k++) {
    unsigned w = sv[t * SEG + k];
    sv[t * SEG + k] = run;
    run += w;
  }
  __syncthreads();
  for (int i = t; i < NB; i += 256) bucketStart[i] = sv[i];
  if (t == 0) bucketStart[NB] = N_EDGES;
}

// chunk-local LDS counting sort by bucket, coalesced-run writes -> packedA = (src<<7)|dl
__global__ __launch_bounds__(256) void scatter_sorted_kernel(
    const int* __restrict__ src, const int* __restrict__ dst,
    const unsigned short* __restrict__ H, const unsigned* __restrict__ P,
    const unsigned* __restrict__ bucketStart, unsigned* __restrict__ packed) {
  __shared__ unsigned ssort[CHUNK];        // 32 KB
  __shared__ unsigned short sbort[CHUNK];  // 16 KB
  __shared__ unsigned hist[3328];          // 13.3 KB
  __shared__ unsigned cur[3328];           // 13.3 KB
  __shared__ unsigned partial[256];
  int t = threadIdx.x;
  int c = blockIdx.x;
  int g = c / CPG;
  long e0 = (long)c * CHUNK;
  long rem = (long)N_EDGES - e0;
  int n = rem > CHUNK ? CHUNK : (int)rem;
  for (int i = t; i < 3328; i += 256) hist[i] = 0;
  __syncthreads();
  for (int i = t; i < n; i += 256) atomicAdd(&hist[dst[e0 + i] >> 6], 1u);
  __syncthreads();
  unsigned a[SEG], sum = 0;
#pragma unroll
  for (int k = 0; k < SEG; k++) { a[k] = hist[SEG * t + k]; sum += a[k]; }
  partial[t] = sum;
  __syncthreads();
  for (int off = 1; off < 256; off <<= 1) {
    unsigned add = (t >= off) ? partial[t - off] : 0u;
    __syncthreads();
    partial[t] += add;
    __syncthreads();
  }
  unsigned run = partial[t] - sum;
#pragma unroll
  for (int k = 0; k < SEG; k++) {
    hist[SEG * t + k] = run;
    cur[SEG * t + k] = run;
    run += a[k];
  }
  __syncthreads();
  for (int i = t; i < n; i += 256) {
    int d = dst[e0 + i], s = src[e0 + i];
    int b = d >> 6;
    unsigned r = atomicAdd(&cur[b], 1u);
    ssort[r] = ((unsigned)s << 7) | (unsigned)(d & 63);
    sbort[r] = (unsigned short)b;
  }
  __syncthreads();
  for (int b = t; b < NB; b += 256)
    cur[b] = bucketStart[b] + P[(size_t)g * NB + b] + H[(size_t)c * NB + b] - hist[b];
  __syncthreads();
  for (int j = t; j < n; j += 256) packed[cur[sbort[j]] + j] = ssort[j];
}

// ---------- partition pass 2: within-bucket sort by node -> full CSR ----------
__global__ __launch_bounds__(256) void sort2_kernel(const unsigned* __restrict__ packedA,
                                                    const unsigned* __restrict__ bucketStart,
                                                    unsigned* __restrict__ packedB,
                                                    unsigned* __restrict__ nodeStart) {
  __shared__ unsigned buf[SCAP];
  __shared__ unsigned buf2[SCAP];
  __shared__ unsigned hist[64], base[64], cur[64];
  int t = threadIdx.x, b = blockIdx.x;
  unsigned s0 = bucketStart[b], s1 = bucketStart[b + 1];
  int n = (int)(s1 - s0);
  if (t < 64) hist[t] = 0;
  for (int i = t; i < n; i += 256) buf[i] = packedA[s0 + i];
  __syncthreads();
  for (int i = t; i < n; i += 256) atomicAdd(&hist[buf[i] & 63u], 1u);
  __syncthreads();
  if (t == 0) {
    unsigned run = 0;
    for (int k = 0; k < 64; k++) {
      unsigned v = hist[k];
      base[k] = run;
      cur[k] = run;
      run += v;
    }
  }
  __syncthreads();
  if (t < 64) nodeStart[b * 64 + t] = s0 + base[t];
  for (int i = t; i < n; i += 256) {
    unsigned p = buf[i];
    unsigned pos = atomicAdd(&cur[p & 63u], 1u);
    buf2[pos] = p >> 7;  // store src only; node implied by CSR position
  }
  __syncthreads();
  for (int i = t; i < n; i += 256) packedB[s0 + i] = buf2[i];
  if (b == NB - 1 && t == 0) nodeStart[N_NODES] = N_EDGES;
}

// ---------- xpad ----------
__global__ __launch_bounds__(256) void xpad_kernel(const float* __restrict__ x,
                                                   float4* __restrict__ xp) {
  int n = blockIdx.x * 256 + threadIdx.x;
  if (n >= N_NODES) return;
  xp[n] = make_float4(x[3 * n], x[3 * n + 1], x[3 * n + 2], 0.f);
}

__device__ __forceinline__ void half8_unpack(uint4 g, float* f) {
  const __half2* h2 = reinterpret_cast<const __half2*>(&g);
#pragma unroll
  for (int j = 0; j < 4; j++) {
    float2 fj = __half22float2(h2[j]);
    f[2 * j] = fj.x;
    f[2 * j + 1] = fj.y;
  }
}

// ---------- layer 1: 4 thr/node, batch-4 independent gathers (R8 form) ----------
__global__ __launch_bounds__(256) void layer1_kernel(
    const unsigned* __restrict__ packed, const unsigned* __restrict__ nodeStart,
    const float4* __restrict__ xp,
    const float* __restrict__ W1_rel, const float* __restrict__ b1,
    const float* __restrict__ W1_root,
    const float* __restrict__ W2_rel, const float* __restrict__ W2_root,
    unsigned* __restrict__ t2h, float* __restrict__ r2) {
  __shared__ float sW1rel[96], sW1root[96], sb1[32], sW2rel[512], sW2root[512];
  __shared__ float plds[256 * 4];
  for (int i = threadIdx.x; i < 96; i += 256) { sW1rel[i] = W1_rel[i]; sW1root[i] = W1_root[i]; }
  for (int i = threadIdx.x; i < 32; i += 256) sb1[i] = b1[i];
  for (int i = threadIdx.x; i < 512; i += 256) { sW2rel[i] = W2_rel[i]; sW2root[i] = W2_root[i]; }
  __syncthreads();
  int t = threadIdx.x, ln = t >> 2, part = t & 3;
  int node = blockIdx.x * 64 + ln;
  unsigned s1v = ntload_u(&nodeStart[node + 1]);
  float a0 = 0.f, a1 = 0.f, a2 = 0.f;
  for (unsigned base = ntload_u(&nodeStart[node]) + part; base < s1v; base += 16) {
    unsigned i1 = base + 4, i2 = base + 8, i3 = base + 12;
    unsigned e0 = ntload_u(&packed[base]);
    unsigned e1 = ntload_u(&packed[i1]);
    unsigned e2 = ntload_u(&packed[i2]);
    unsigned e3 = ntload_u(&packed[i3]);
    float4 g0 = xp[e0], g1 = xp[e1], g2 = xp[e2], g3 = xp[e3];
    float m1 = (i1 < s1v) ? 1.f : 0.f;
    float m2 = (i2 < s1v) ? 1.f : 0.f;
    float m3 = (i3 < s1v) ? 1.f : 0.f;
    a0 += g0.x + m1 * g1.x + m2 * g2.x + m3 * g3.x;
    a1 += g0.y + m1 * g1.y + m2 * g2.y + m3 * g3.y;
    a2 += g0.z + m1 * g1.z + m2 * g2.z + m3 * g3.z;
  }
  plds[t * 4] = a0; plds[t * 4 + 1] = a1; plds[t * 4 + 2] = a2;
  __syncthreads();
  int pb = ln * 16;
  float A0 = plds[pb] + plds[pb + 4] + plds[pb + 8] + plds[pb + 12];
  float A1 = plds[pb + 1] + plds[pb + 5] + plds[pb + 9] + plds[pb + 13];
  float A2 = plds[pb + 2] + plds[pb + 6] + plds[pb + 10] + plds[pb + 14];
  float4 xv = xp[node];
  float h[32];
#pragma unroll
  for (int k = 0; k < 32; k++) {
    float v = sW1rel[3 * k] * A0 + sW1rel[3 * k + 1] * A1 + sW1rel[3 * k + 2] * A2 +
              sW1root[3 * k] * xv.x + sW1root[3 * k + 1] * xv.y + sW1root[3 * k + 2] * xv.z +
              sb1[k];
    h[k] = fmaxf(v, 0.f);
  }
  int jb = part * 4;
  float tv[4], rv[4];
#pragma unroll
  for (int j = 0; j < 4; j++) {
    float acc = 0.f, accr = 0.f;
#pragma unroll
    for (int k = 0; k < 32; k++) {
      acc += sW2rel[32 * (jb + j) + k] * h[k];
      accr += sW2root[32 * (jb + j) + k] * h[k];
    }
    tv[j] = acc;
    rv[j] = accr;
  }
  __half2 p0 = __halves2half2(__float2half_rn(tv[0]), __float2half_rn(tv[1]));
  __half2 p1 = __halves2half2(__float2half_rn(tv[2]), __float2half_rn(tv[3]));
  ntstore_u2(&t2h[(size_t)node * 8 + part * 2], make_uint2(*(unsigned*)&p0, *(unsigned*)&p1));
  ntstore_f4(&r2[(size_t)node * 16 + jb], make_float4(rv[0], rv[1], rv[2], rv[3]));
}

// ---------- layer 2: 8 thr/node (pair x half), batch-4 independent gathers (R8 form) ----------
__global__ __launch_bounds__(256) void layer2_kernel(
    const unsigned* __restrict__ packed, const unsigned* __restrict__ nodeStart,
    const uint4* __restrict__ t2h4, const float* __restrict__ r2,
    const float* __restrict__ b2,
    const float* __restrict__ W3_rel, const float* __restrict__ W3_root,
    unsigned* __restrict__ t3h, float* __restrict__ r3) {
  __shared__ float sW3rel[128], sW3root[128], sb2[16];
  __shared__ float plds[256 * 9];  // stride 9: conflict-free combine
  __shared__ float hlds[32 * 16];
  for (int i = threadIdx.x; i < 128; i += 256) { sW3rel[i] = W3_rel[i]; sW3root[i] = W3_root[i]; }
  if (threadIdx.x < 16) sb2[threadIdx.x] = b2[threadIdx.x];
  __syncthreads();
  int t = threadIdx.x, ln = t >> 3, p = t & 7;
  int node = blockIdx.x * 32 + ln;
  int half = p & 1;  // which 16B of the 32B record
  unsigned s1v = ntload_u(&nodeStart[node + 1]);
  float acc[8];
#pragma unroll
  for (int j = 0; j < 8; j++) acc[j] = 0.f;
  for (unsigned base = ntload_u(&nodeStart[node]) + (p >> 1); base < s1v; base += 16) {
    unsigned i1 = base + 4, i2 = base + 8, i3 = base + 12;
    unsigned e0 = ntload_u(&packed[base]);
    unsigned e1 = ntload_u(&packed[i1]);
    unsigned e2 = ntload_u(&packed[i2]);
    unsigned e3 = ntload_u(&packed[i3]);
    uint4 g0 = t2h4[(size_t)e0 * 2 + half];
    uint4 g1 = t2h4[(size_t)e1 * 2 + half];
    uint4 g2 = t2h4[(size_t)e2 * 2 + half];
    uint4 g3 = t2h4[(size_t)e3 * 2 + half];
    float m1 = (i1 < s1v) ? 1.f : 0.f;
    float m2 = (i2 < s1v) ? 1.f : 0.f;
    float m3 = (i3 < s1v) ? 1.f : 0.f;
    float f0[8], f1[8], f2[8], f3[8];
    half8_unpack(g0, f0);
    half8_unpack(g1, f1);
    half8_unpack(g2, f2);
    half8_unpack(g3, f3);
#pragma unroll
    for (int j = 0; j < 8; j++)
      acc[j] += f0[j] + m1 * f1[j] + m2 * f2[j] + m3 * f3[j];
  }
#pragma unroll
  for (int j = 0; j < 8; j++) plds[t * 9 + j] = acc[j];
  __syncthreads();
  // h: thread computes feats 2p, 2p+1
  {
    float2 rv = ntload_f2(&r2[(size_t)node * 16 + 2 * p]);
    float hv[2];
#pragma unroll
    for (int k2 = 0; k2 < 2; k2++) {
      int f = 2 * p + k2;
      int fh = f >> 3, fi = f & 7;
      int q0 = (ln * 8 + fh) * 9 + fi;
      float s = plds[q0] + plds[q0 + 18] + plds[q0 + 36] + plds[q0 + 54];
      hv[k2] = s + sb2[f] + (k2 == 0 ? rv.x : rv.y);
    }
    hlds[ln * 16 + 2 * p] = fmaxf(hv[0], 0.f);
    hlds[ln * 16 + 2 * p + 1] = fmaxf(hv[1], 0.f);
  }
  __syncthreads();
  // rows: p<4 -> W3_rel rows 2p,2p+1 (t3); p>=4 -> W3_root rows 2(p-4).. (r3)
  const float* W = (p < 4) ? sW3rel : sW3root;
  int rbase = (p < 4) ? 2 * p : 2 * (p - 4);
  float o0 = 0.f, o1 = 0.f;
#pragma unroll
  for (int k = 0; k < 16; k++) {
    float hv = hlds[ln * 16 + k];
    o0 += W[16 * rbase + k] * hv;
    o1 += W[16 * (rbase + 1) + k] * hv;
  }
  if (p < 4) {
    __half2 pk = __halves2half2(__float2half_rn(o0), __float2half_rn(o1));
    ntstore_u(&t3h[(size_t)node * 4 + p], *(unsigned*)&pk);
  } else {
    ntstore_f2(&r3[(size_t)node * 8 + rbase], make_float2(o0, o1));
  }
}

// ---------- layer 3: 8 thr/node, batch-4 independent gathers (R8 form) ----------
__global__ __launch_bounds__(256) void layer3_kernel(
    const unsigned* __restrict__ packed, const unsigned* __restrict__ nodeStart,
    const uint4* __restrict__ t3h4, const float* __restrict__ r3,
    const float* __restrict__ b3,
    const int* __restrict__ batch, unsigned* __restrict__ pooled) {
  __shared__ float plds[256 * 9];
  __shared__ float sb3[8];
  if (threadIdx.x < 8) sb3[threadIdx.x] = b3[threadIdx.x];
  __syncthreads();
  int t = threadIdx.x, ln = t >> 3, p = t & 7;
  int node = blockIdx.x * 32 + ln;
  unsigned s1v = ntload_u(&nodeStart[node + 1]);
  float acc[8];
#pragma unroll
  for (int j = 0; j < 8; j++) acc[j] = 0.f;
  for (unsigned base = ntload_u(&nodeStart[node]) + p; base < s1v; base += 32) {
    unsigned i1 = base + 8, i2 = base + 16, i3 = base + 24;
    unsigned e0 = ntload_u(&packed[base]);
    unsigned e1 = ntload_u(&packed[i1]);
    unsigned e2 = ntload_u(&packed[i2]);
    unsigned e3 = ntload_u(&packed[i3]);
    uint4 g0 = t3h4[e0];
    uint4 g1 = t3h4[e1];
    uint4 g2 = t3h4[e2];
    uint4 g3 = t3h4[e3];
    float m1 = (i1 < s1v) ? 1.f : 0.f;
    float m2 = (i2 < s1v) ? 1.f : 0.f;
    float m3 = (i3 < s1v) ? 1.f : 0.f;
    float f0[8], f1[8], f2[8], f3[8];
    half8_unpack(g0, f0);
    half8_unpack(g1, f1);
    half8_unpack(g2, f2);
    half8_unpack(g3, f3);
#pragma unroll
    for (int j = 0; j < 8; j++)
      acc[j] += f0[j] + m1 * f1[j] + m2 * f2[j] + m3 * f3[j];
  }
#pragma unroll
  for (int j = 0; j < 8; j++) plds[t * 9 + j] = acc[j];
  __syncthreads();
  int gg = ntload_i(&batch[node]);
  int q0 = ln * 72 + p;  // (ln*8+k)*9 + p, k=0..7
  float v = plds[q0] + plds[q0 + 9] + plds[q0 + 18] + plds[q0 + 27] +
            plds[q0 + 36] + plds[q0 + 45] + plds[q0 + 54] + plds[q0 + 63];
  float h = fmaxf(v + sb3[p] + ntload_f(&r3[(size_t)node * 8 + p]), 0.f);
  atomicMax(&pooled[8 * gg + p], __float_as_uint(h));  // relu>=0: uint order==float order
}

__global__ __launch_bounds__(256) void final_kernel(
    const unsigned* __restrict__ pooled, const float* __restrict__ W_lin,
    const float* __restrict__ b_lin, float* __restrict__ out) {
  int g = blockIdx.x * blockDim.x + threadIdx.x;
  if (g >= N_GRAPHS) return;
  float acc = b_lin[0];
#pragma unroll
  for (int f = 0; f < 8; f++) acc += __uint_as_float(pooled[8 * g + f]) * W_lin[f];
  out[g] = acc;
}

extern "C" void kernel_launch(void* const* d_in, const int* in_sizes, int n_in,
                              void* d_out, int out_size, void* d_ws, size_t ws_size,
                              hipStream_t stream) {
  const float* x = (const float*)d_in[0];
  const int* ei = (const int*)d_in[1];
  const int* src = ei;
  const int* dst = ei + N_EDGES;
  const int* batch = (const int*)d_in[2];
  const float* W1_rel = (const float*)d_in[3];
  const float* b1 = (const float*)d_in[4];
  const float* W1_root = (const float*)d_in[5];
  const float* W2_rel = (const float*)d_in[6];
  const float* b2 = (const float*)d_in[7];
  const float* W2_root = (const float*)d_in[8];
  const float* W3_rel = (const float*)d_in[9];
  const float* b3 = (const float*)d_in[10];
  const float* W3_root = (const float*)d_in[11];
  const float* W_lin = (const float*)d_in[12];
  const float* b_lin = (const float*)d_in[13];
  float* out = (float*)d_out;

  // ---- workspace layout (bytes), same as R8 ----
  char* ws = (char*)d_ws;
  unsigned* packedA = (unsigned*)(ws + 0);                // 25,600,000
  float* r2 = (float*)(ws + 0);                           // 12,800,000 (alias, post-sort2)
  float* r3 = (float*)(ws + 12800000);                    // 6,400,000
  unsigned* t3h = (unsigned*)(ws + 19200000);             // 3,200,000
  float4* xpad = (float4*)(ws + 22400000);                // 3,200,000
  unsigned short* H = (unsigned short*)(ws + 25600000);   // 4,887,500 (dead before packedB)
  unsigned* packedB = (unsigned*)(ws + 25600000);         // 25,600,000 + 128 pad
  unsigned* t2h = (unsigned*)(ws + 51200128);             // 6,400,000
  unsigned* pooled = (unsigned*)(ws + 57600128);          // 16,384
  unsigned* bucketStart = (unsigned*)(ws + 57616512);     // 12,504 (NB+1)
  unsigned* bucketTotal = (unsigned*)(ws + 57629016);     // 12,500
  unsigned* P = (unsigned*)(ws + 57641516);               // 312,500
  unsigned* nodeStart = (unsigned*)(ws + 57954016);       // 800,004 -> end 58,754,020

  hipMemsetAsync(pooled, 0, N_GRAPHS * 8 * sizeof(unsigned), stream);
  hipMemsetAsync(packedB + N_EDGES, 0, 128, stream);  // batch-4 overrun pad (src=0 safe)

  // partition: two-level counting sort to full dst-CSR (CHUNK=8192)
  count_kernel<<<NCH, 256, 0, stream>>>(dst, H);
  scan_bins1_kernel<<<dim3((NB + 255) / 256, NGRP), 256, 0, stream>>>(H, P);
  scan_bins2_kernel<<<(NB + 255) / 256, 256, 0, stream>>>(P, bucketTotal);
  scan_total_kernel<<<1, 256, 0, stream>>>(bucketTotal, bucketStart);
  scatter_sorted_kernel<<<NCH, 256, 0, stream>>>(src, dst, H, P, bucketStart, packedA);
  sort2_kernel<<<NB, 256, 0, stream>>>(packedA, bucketStart, packedB, nodeStart);
  xpad_kernel<<<(N_NODES + 255) / 256, 256, 0, stream>>>(x, xpad);  // after sort2 (aliases packedA)

  // layers: atomic-free register accumulation, batch-4 independent gathers (R8 forms)
  layer1_kernel<<<NB, 256, 0, stream>>>(packedB, nodeStart, xpad,
                                        W1_rel, b1, W1_root, W2_rel, W2_root, t2h, r2);
  layer2_kernel<<<N_NODES / 32, 256, 0, stream>>>(packedB, nodeStart, (const uint4*)t2h, r2, b2,
                                                  W3_rel, W3_root, t3h, r3);
  layer3_kernel<<<N_NODES / 32, 256, 0, stream>>>(packedB, nodeStart, (const uint4*)t3h, r3, b3,
                                                  batch, pooled);
  final_kernel<<<(N_GRAPHS + 255) / 256, 256, 0, stream>>>(pooled, W_lin, b_lin, out);
}